// Round 1
// baseline (8530.345 us; speedup 1.0000x reference)
//
#include <hip/hip_runtime.h>
#include <math.h>

#define B_    4096
#define A_    6
#define V_    1024
#define L_    32
#define DIN_  64
#define DOUT_ 64
#define H_    512
#define G_    2048   // 4*H
#define ROWS  16
#define NT    1024

// ---------------- transpose helper (once per launch, tiny) ----------------
__global__ void tr_kernel(const float* __restrict__ A, float* __restrict__ At,
                          int R, int C) {
  __shared__ float tile[32][33];
  int c0 = blockIdx.x * 32, r0 = blockIdx.y * 32;
  int tx = threadIdx.x, ty = threadIdx.y;
  #pragma unroll
  for (int i = ty; i < 32; i += 8)
    tile[i][tx] = A[(size_t)(r0 + i) * C + (c0 + tx)];
  __syncthreads();
  #pragma unroll
  for (int i = ty; i < 32; i += 8)
    At[(size_t)(c0 + i) * R + (r0 + tx)] = tile[tx][i];
}

// ---------------- fused 32-step LSTM greedy decoder ----------------
// One block owns 16 batch rows for the whole sequence. No cross-block deps.
template <bool TR>
__launch_bounds__(NT, 1)
__global__ void lstm_decode(
    const int*   __restrict__ x,          // [B][A]
    const float* __restrict__ input_emb,  // [NE][DIN]
    const float* __restrict__ output_emb, // [V][DOUT]
    const float* __restrict__ Wi,         // [A*DIN][H]
    const float* __restrict__ bi,         // [H]
    const float* __restrict__ Wih,        // TR ? W_ihT [DOUT][G] : W_ih [G][DOUT]
    const float* __restrict__ Whh,        // TR ? W_hhT [H][G]    : W_hh [G][H]
    const float* __restrict__ b_ih,       // [G]
    const float* __restrict__ b_hh,       // [G]
    const float* __restrict__ Wo,         // [H][V]
    const float* __restrict__ bo,         // [V]
    const float* __restrict__ sos,        // [DOUT]
    float* __restrict__ out)              // seq [B][L] then logits [B][L][V]
{
  __shared__ __align__(16) float sh[ROWS * H_];          // hidden state, 32 KB
  __shared__ __align__(16) float semb[ROWS * DOUT_];     // fed-back emb, 4 KB
  __shared__ __align__(16) float sbuf[ROWS * A_ * DIN_]; // prologue e / argmax cands, 24 KB

  const int t     = threadIdx.x;
  const int r0    = blockIdx.x * ROWS;
  const int j     = t & (H_ - 1);     // hidden column this thread owns
  const int rbase = (t >> 9) * 8;     // rows rbase..rbase+7

  float* out_seq    = out;
  float* out_logits = out + (size_t)B_ * L_;

  // ---- prologue: gather e = input_emb[x], init emb = sos ----
  for (int idx = t; idx < ROWS * A_ * DIN_; idx += NT) {
    int r   = idx / (A_ * DIN_);
    int rem = idx - r * (A_ * DIN_);
    int a   = rem >> 6;
    int d   = rem & 63;
    int ei  = x[(r0 + r) * A_ + a];
    sbuf[idx] = input_emb[ei * DIN_ + d];
  }
  for (int idx = t; idx < ROWS * DOUT_; idx += NT)
    semb[idx] = sos[idx & 63];
  __syncthreads();

  // ---- h0 = e @ Wi + bi ----
  {
    float acc[8];
    #pragma unroll
    for (int r = 0; r < 8; r++) acc[r] = 0.f;
    for (int k = 0; k < A_ * DIN_; k++) {
      float w = Wi[(size_t)k * H_ + j];
      #pragma unroll
      for (int r = 0; r < 8; r++)
        acc[r] = fmaf(sbuf[(rbase + r) * (A_ * DIN_) + k], w, acc[r]);
    }
    float bj = bi[j];
    #pragma unroll
    for (int r = 0; r < 8; r++)
      sh[(rbase + r) * H_ + j] = acc[r] + bj;
  }
  __syncthreads();

  // persistent per-thread state
  float creg[8];
  #pragma unroll
  for (int r = 0; r < 8; r++) creg[r] = 0.f;
  const float bii = b_ih[j]        + b_hh[j];
  const float bff = b_ih[j + 512]  + b_hh[j + 512];
  const float bgg = b_ih[j + 1024] + b_hh[j + 1024];
  const float boo = b_ih[j + 1536] + b_hh[j + 1536];
  const float bov = bo[t];

  float* cand_v = sbuf;                  // [16 rows][16 waves]
  int*   cand_i = (int*)(sbuf + 256);
  int*   sym_sh = (int*)(sbuf + 512);

  for (int step = 0; step < L_; step++) {
    // ---------- gates = bias + emb @ W_ih^T + h @ W_hh^T ----------
    float ai[8], af[8], ag[8], ao[8];
    #pragma unroll
    for (int r = 0; r < 8; r++) { ai[r] = bii; af[r] = bff; ag[r] = bgg; ao[r] = boo; }

    // emb part (K = 64)
    for (int k = 0; k < DOUT_; k += 4) {
      float w[4][4];
      if (TR) {
        #pragma unroll
        for (int kk = 0; kk < 4; kk++) {
          const float* p = Wih + (size_t)(k + kk) * G_ + j;
          w[kk][0] = p[0]; w[kk][1] = p[512]; w[kk][2] = p[1024]; w[kk][3] = p[1536];
        }
      } else {
        #pragma unroll
        for (int gi = 0; gi < 4; gi++) {
          float4 w4 = *(const float4*)&Wih[(size_t)(j + gi * 512) * DOUT_ + k];
          w[0][gi] = w4.x; w[1][gi] = w4.y; w[2][gi] = w4.z; w[3][gi] = w4.w;
        }
      }
      #pragma unroll
      for (int r = 0; r < 8; r++) {
        float4 e4 = *(const float4*)&semb[(rbase + r) * DOUT_ + k];
        ai[r] = fmaf(e4.x, w[0][0], ai[r]); af[r] = fmaf(e4.x, w[0][1], af[r]);
        ag[r] = fmaf(e4.x, w[0][2], ag[r]); ao[r] = fmaf(e4.x, w[0][3], ao[r]);
        ai[r] = fmaf(e4.y, w[1][0], ai[r]); af[r] = fmaf(e4.y, w[1][1], af[r]);
        ag[r] = fmaf(e4.y, w[1][2], ag[r]); ao[r] = fmaf(e4.y, w[1][3], ao[r]);
        ai[r] = fmaf(e4.z, w[2][0], ai[r]); af[r] = fmaf(e4.z, w[2][1], af[r]);
        ag[r] = fmaf(e4.z, w[2][2], ag[r]); ao[r] = fmaf(e4.z, w[2][3], ao[r]);
        ai[r] = fmaf(e4.w, w[3][0], ai[r]); af[r] = fmaf(e4.w, w[3][1], af[r]);
        ag[r] = fmaf(e4.w, w[3][2], ag[r]); ao[r] = fmaf(e4.w, w[3][3], ao[r]);
      }
    }
    // h part (K = 512)
    for (int k = 0; k < H_; k += 4) {
      float w[4][4];
      if (TR) {
        #pragma unroll
        for (int kk = 0; kk < 4; kk++) {
          const float* p = Whh + (size_t)(k + kk) * G_ + j;
          w[kk][0] = p[0]; w[kk][1] = p[512]; w[kk][2] = p[1024]; w[kk][3] = p[1536];
        }
      } else {
        #pragma unroll
        for (int gi = 0; gi < 4; gi++) {
          float4 w4 = *(const float4*)&Whh[(size_t)(j + gi * 512) * H_ + k];
          w[0][gi] = w4.x; w[1][gi] = w4.y; w[2][gi] = w4.z; w[3][gi] = w4.w;
        }
      }
      #pragma unroll
      for (int r = 0; r < 8; r++) {
        float4 h4 = *(const float4*)&sh[(rbase + r) * H_ + k];
        ai[r] = fmaf(h4.x, w[0][0], ai[r]); af[r] = fmaf(h4.x, w[0][1], af[r]);
        ag[r] = fmaf(h4.x, w[0][2], ag[r]); ao[r] = fmaf(h4.x, w[0][3], ao[r]);
        ai[r] = fmaf(h4.y, w[1][0], ai[r]); af[r] = fmaf(h4.y, w[1][1], af[r]);
        ag[r] = fmaf(h4.y, w[1][2], ag[r]); ao[r] = fmaf(h4.y, w[1][3], ao[r]);
        ai[r] = fmaf(h4.z, w[2][0], ai[r]); af[r] = fmaf(h4.z, w[2][1], af[r]);
        ag[r] = fmaf(h4.z, w[2][2], ag[r]); ao[r] = fmaf(h4.z, w[2][3], ao[r]);
        ai[r] = fmaf(h4.w, w[3][0], ai[r]); af[r] = fmaf(h4.w, w[3][1], af[r]);
        ag[r] = fmaf(h4.w, w[3][2], ag[r]); ao[r] = fmaf(h4.w, w[3][3], ao[r]);
      }
    }

    // ---------- activations; c kept in registers ----------
    float hn[8];
    #pragma unroll
    for (int r = 0; r < 8; r++) {
      float iv = 1.f / (1.f + expf(-ai[r]));
      float fv = 1.f / (1.f + expf(-af[r]));
      float gv = tanhf(ag[r]);
      float ov = 1.f / (1.f + expf(-ao[r]));
      float cn = fv * creg[r] + iv * gv;
      creg[r]  = cn;
      hn[r]    = ov * tanhf(cn);
    }
    __syncthreads();                      // everyone done READING sh/semb
    #pragma unroll
    for (int r = 0; r < 8; r++)
      sh[(rbase + r) * H_ + j] = hn[r];
    __syncthreads();                      // new h visible

    // ---------- logits: thread owns vocab column v = t ----------
    float lacc[16];
    #pragma unroll
    for (int r = 0; r < 16; r++) lacc[r] = bov;
    for (int k = 0; k < H_; k += 4) {
      float w0 = Wo[(size_t)(k + 0) * V_ + t];
      float w1 = Wo[(size_t)(k + 1) * V_ + t];
      float w2 = Wo[(size_t)(k + 2) * V_ + t];
      float w3 = Wo[(size_t)(k + 3) * V_ + t];
      #pragma unroll
      for (int r = 0; r < 16; r++) {
        float4 h4 = *(const float4*)&sh[r * H_ + k];
        lacc[r] = fmaf(h4.x, w0, lacc[r]);
        lacc[r] = fmaf(h4.y, w1, lacc[r]);
        lacc[r] = fmaf(h4.z, w2, lacc[r]);
        lacc[r] = fmaf(h4.w, w3, lacc[r]);
      }
    }
    #pragma unroll
    for (int r = 0; r < 16; r++)
      out_logits[((size_t)(r0 + r) * L_ + step) * V_ + t] = lacc[r];

    // ---------- argmax (numpy semantics: first index wins on ties) ----------
    const int lane = t & 63;
    const int wv   = t >> 6;
    #pragma unroll
    for (int r = 0; r < 16; r++) {
      float bv = lacc[r];
      int   bx = t;
      #pragma unroll
      for (int off = 32; off; off >>= 1) {
        float ov = __shfl_xor(bv, off);
        int   ox = __shfl_xor(bx, off);
        if (ov > bv || (ov == bv && ox < bx)) { bv = ov; bx = ox; }
      }
      if (lane == 0) { cand_v[r * 16 + wv] = bv; cand_i[r * 16 + wv] = bx; }
    }
    __syncthreads();
    if (t < 16) {
      float bv = cand_v[t * 16 + 0];
      int   bx = cand_i[t * 16 + 0];
      #pragma unroll
      for (int c = 1; c < 16; c++) {
        float ov = cand_v[t * 16 + c];
        int   ox = cand_i[t * 16 + c];
        if (ov > bv || (ov == bv && ox < bx)) { bv = ov; bx = ox; }
      }
      sym_sh[t] = bx;
      out_seq[(size_t)(r0 + t) * L_ + step] = (float)bx;   // whole buffer is f32
    }
    __syncthreads();

    // ---------- emb feedback ----------
    {
      int r = t >> 6;
      int d = t & 63;
      semb[r * DOUT_ + d] = output_emb[(size_t)sym_sh[r] * DOUT_ + d];
    }
    __syncthreads();
  }
}

extern "C" void kernel_launch(void* const* d_in, const int* in_sizes, int n_in,
                              void* d_out, int out_size, void* d_ws, size_t ws_size,
                              hipStream_t stream) {
  const int*   x          = (const int*)  d_in[0];
  const float* input_emb  = (const float*)d_in[1];
  const float* output_emb = (const float*)d_in[2];
  const float* Wi         = (const float*)d_in[3];
  const float* bi         = (const float*)d_in[4];
  const float* W_ih       = (const float*)d_in[5];
  const float* W_hh       = (const float*)d_in[6];
  const float* b_ih       = (const float*)d_in[7];
  const float* b_hh       = (const float*)d_in[8];
  const float* Wo         = (const float*)d_in[9];
  const float* bo         = (const float*)d_in[10];
  const float* sos        = (const float*)d_in[11];
  float* out = (float*)d_out;

  const size_t ws_need = ((size_t)H_ * G_ + (size_t)DOUT_ * G_) * sizeof(float);

  if (ws_size >= ws_need) {
    float* W_hhT = (float*)d_ws;            // [H][G]
    float* W_ihT = W_hhT + (size_t)H_ * G_; // [DOUT][G]
    dim3 tb(32, 8);
    tr_kernel<<<dim3(H_ / 32,    G_ / 32), tb, 0, stream>>>(W_hh, W_hhT, G_, H_);
    tr_kernel<<<dim3(DOUT_ / 32, G_ / 32), tb, 0, stream>>>(W_ih, W_ihT, G_, DOUT_);
    lstm_decode<true><<<B_ / ROWS, NT, 0, stream>>>(
        x, input_emb, output_emb, Wi, bi, W_ihT, W_hhT, b_ih, b_hh, Wo, bo, sos, out);
  } else {
    lstm_decode<false><<<B_ / ROWS, NT, 0, stream>>>(
        x, input_emb, output_emb, Wi, bi, W_ih, W_hh, b_ih, b_hh, Wo, bo, sos, out);
  }
}

// Round 2
// 8316.098 us; speedup vs baseline: 1.0258x; 1.0258x over previous
//
#include <hip/hip_runtime.h>
#include <math.h>

#define B_    4096
#define A_    6
#define V_    1024
#define L_    32
#define DIN_  64
#define DOUT_ 64
#define H_    512
#define G_    2048   // 4*H
#define ROWS  16
#define NT    1024

// ---------- pack W_ih / W_hh: [4*512][K] -> [K][512] float4 (i,f,g,o) ----------
__global__ void pack_gates(const float* __restrict__ W, float4* __restrict__ Wp, int K) {
  __shared__ float tile[4][32][33];
  int k0 = blockIdx.x * 32, j0 = blockIdx.y * 32;
  int tx = threadIdx.x, ty = threadIdx.y;            // 32 x 8
  #pragma unroll
  for (int gi = 0; gi < 4; gi++)
    for (int i = ty; i < 32; i += 8)
      tile[gi][i][tx] = W[(size_t)(gi * 512 + j0 + i) * K + (k0 + tx)];
  __syncthreads();
  for (int i = ty; i < 32; i += 8) {
    float4 v = make_float4(tile[0][tx][i], tile[1][tx][i], tile[2][tx][i], tile[3][tx][i]);
    Wp[(size_t)(k0 + i) * 512 + (j0 + tx)] = v;
  }
}

// ---------- pack Wo: [512][1024] -> [128][1024] float4 (k,k+1,k+2,k+3) ----------
__global__ void pack_wo(const float* __restrict__ Wo, float4* __restrict__ Wp) {
  int v  = blockIdx.x * 256 + threadIdx.x;
  int k4 = blockIdx.y;
  Wp[(size_t)k4 * 1024 + v] = make_float4(
      Wo[(size_t)(4 * k4 + 0) * 1024 + v], Wo[(size_t)(4 * k4 + 1) * 1024 + v],
      Wo[(size_t)(4 * k4 + 2) * 1024 + v], Wo[(size_t)(4 * k4 + 3) * 1024 + v]);
}

// ---------------- fused 32-step LSTM greedy decoder ----------------
// One block owns 16 batch rows for the whole sequence. No cross-block deps.
// PK=true: Wih/Whh are float4-packed [K][512], Wo is float4-packed [128][1024].
template <bool PK>
__launch_bounds__(NT, 1)
__global__ void lstm_decode(
    const int*   __restrict__ x,
    const float* __restrict__ input_emb,
    const float* __restrict__ output_emb,
    const float* __restrict__ Wi,         // [A*DIN][H] raw
    const float* __restrict__ bi,
    const float* __restrict__ Wih,        // PK ? packed : raw [G][DOUT]
    const float* __restrict__ Whh,        // PK ? packed : raw [G][H]
    const float* __restrict__ b_ih,
    const float* __restrict__ b_hh,
    const float* __restrict__ Wo,         // PK ? packed : raw [H][V]
    const float* __restrict__ bo,
    const float* __restrict__ sos,
    float* __restrict__ out)              // seq [B][L] then logits [B][L][V]
{
  __shared__ __align__(16) float sh[ROWS * H_];          // hidden state, 32 KB
  __shared__ __align__(16) float semb[ROWS * DOUT_];     // fed-back emb, 4 KB
  __shared__ __align__(16) float sbuf[ROWS * A_ * DIN_]; // prologue e / argmax cands, 24 KB

  const int t     = threadIdx.x;
  const int r0    = blockIdx.x * ROWS;
  const int j     = t & (H_ - 1);     // hidden column this thread owns
  const int rbase = (t >> 9) * 8;     // rows rbase..rbase+7

  float* out_seq    = out;
  float* out_logits = out + (size_t)B_ * L_;

  // ---- prologue: gather e = input_emb[x], init emb = sos ----
  for (int idx = t; idx < ROWS * A_ * DIN_; idx += NT) {
    int r   = idx / (A_ * DIN_);
    int rem = idx - r * (A_ * DIN_);
    int a   = rem >> 6;
    int d   = rem & 63;
    int ei  = x[(r0 + r) * A_ + a];
    sbuf[idx] = input_emb[ei * DIN_ + d];
  }
  for (int idx = t; idx < ROWS * DOUT_; idx += NT)
    semb[idx] = sos[idx & 63];
  __syncthreads();

  // ---- h0 = e @ Wi + bi ----
  {
    float acc[8];
    #pragma unroll
    for (int r = 0; r < 8; r++) acc[r] = 0.f;
    for (int k = 0; k < A_ * DIN_; k++) {
      float w = Wi[(size_t)k * H_ + j];
      #pragma unroll
      for (int r = 0; r < 8; r++)
        acc[r] = fmaf(sbuf[(rbase + r) * (A_ * DIN_) + k], w, acc[r]);
    }
    float bj = bi[j];
    #pragma unroll
    for (int r = 0; r < 8; r++)
      sh[(rbase + r) * H_ + j] = acc[r] + bj;
  }
  __syncthreads();

  // persistent per-thread state
  float creg[8];
  #pragma unroll
  for (int r = 0; r < 8; r++) creg[r] = 0.f;
  const float bii = b_ih[j]        + b_hh[j];
  const float bff = b_ih[j + 512]  + b_hh[j + 512];
  const float bgg = b_ih[j + 1024] + b_hh[j + 1024];
  const float boo = b_ih[j + 1536] + b_hh[j + 1536];
  const float bov = bo[t];

  float* cand_v = sbuf;                  // [16 rows][16 waves]
  int*   cand_i = (int*)(sbuf + 256);
  int*   sym_sh = (int*)(sbuf + 512);

  const float4* WpE = (const float4*)Wih;   // [64][512]  (PK)
  const float4* WpH = (const float4*)Whh;   // [512][512] (PK)
  const float4* Wop = (const float4*)Wo;    // [128][1024](PK)

  for (int step = 0; step < L_; step++) {
    // ---------- gates = bias + emb @ W_ih^T + h @ W_hh^T ----------
    float ai[8], af[8], ag[8], ao[8];
    #pragma unroll
    for (int r = 0; r < 8; r++) { ai[r] = bii; af[r] = bff; ag[r] = bgg; ao[r] = boo; }

    if (PK) {
      // ---- emb part (K = 64), packed float4 weights, depth-1 prefetch ----
      float4 w0 = WpE[0 * 512 + j], w1 = WpE[1 * 512 + j],
             w2 = WpE[2 * 512 + j], w3 = WpE[3 * 512 + j];
      #pragma unroll 2
      for (int k = 0; k < DOUT_; k += 4) {
        const int kn = (k + 4 < DOUT_) ? (k + 4) : 0;
        float4 n0 = WpE[(size_t)(kn + 0) * 512 + j];
        float4 n1 = WpE[(size_t)(kn + 1) * 512 + j];
        float4 n2 = WpE[(size_t)(kn + 2) * 512 + j];
        float4 n3 = WpE[(size_t)(kn + 3) * 512 + j];
        #pragma unroll
        for (int r = 0; r < 8; r++) {
          float4 e4 = *(const float4*)&semb[(rbase + r) * DOUT_ + k];
          ai[r]=fmaf(e4.x,w0.x,ai[r]); af[r]=fmaf(e4.x,w0.y,af[r]); ag[r]=fmaf(e4.x,w0.z,ag[r]); ao[r]=fmaf(e4.x,w0.w,ao[r]);
          ai[r]=fmaf(e4.y,w1.x,ai[r]); af[r]=fmaf(e4.y,w1.y,af[r]); ag[r]=fmaf(e4.y,w1.z,ag[r]); ao[r]=fmaf(e4.y,w1.w,ao[r]);
          ai[r]=fmaf(e4.z,w2.x,ai[r]); af[r]=fmaf(e4.z,w2.y,af[r]); ag[r]=fmaf(e4.z,w2.z,ag[r]); ao[r]=fmaf(e4.z,w2.w,ao[r]);
          ai[r]=fmaf(e4.w,w3.x,ai[r]); af[r]=fmaf(e4.w,w3.y,af[r]); ag[r]=fmaf(e4.w,w3.z,ag[r]); ao[r]=fmaf(e4.w,w3.w,ao[r]);
        }
        w0 = n0; w1 = n1; w2 = n2; w3 = n3;
      }
      // ---- h part (K = 512), packed float4 weights, depth-1 prefetch ----
      float4 v0 = WpH[0 * 512 + j], v1 = WpH[1 * 512 + j],
             v2 = WpH[2 * 512 + j], v3 = WpH[3 * 512 + j];
      #pragma unroll 2
      for (int k = 0; k < H_; k += 4) {
        const int kn = (k + 4 < H_) ? (k + 4) : 0;
        float4 n0 = WpH[(size_t)(kn + 0) * 512 + j];
        float4 n1 = WpH[(size_t)(kn + 1) * 512 + j];
        float4 n2 = WpH[(size_t)(kn + 2) * 512 + j];
        float4 n3 = WpH[(size_t)(kn + 3) * 512 + j];
        #pragma unroll
        for (int r = 0; r < 8; r++) {
          float4 h4 = *(const float4*)&sh[(rbase + r) * H_ + k];
          ai[r]=fmaf(h4.x,v0.x,ai[r]); af[r]=fmaf(h4.x,v0.y,af[r]); ag[r]=fmaf(h4.x,v0.z,ag[r]); ao[r]=fmaf(h4.x,v0.w,ao[r]);
          ai[r]=fmaf(h4.y,v1.x,ai[r]); af[r]=fmaf(h4.y,v1.y,af[r]); ag[r]=fmaf(h4.y,v1.z,ag[r]); ao[r]=fmaf(h4.y,v1.w,ao[r]);
          ai[r]=fmaf(h4.z,v2.x,ai[r]); af[r]=fmaf(h4.z,v2.y,af[r]); ag[r]=fmaf(h4.z,v2.z,ag[r]); ao[r]=fmaf(h4.z,v2.w,ao[r]);
          ai[r]=fmaf(h4.w,v3.x,ai[r]); af[r]=fmaf(h4.w,v3.y,af[r]); ag[r]=fmaf(h4.w,v3.z,ag[r]); ao[r]=fmaf(h4.w,v3.w,ao[r]);
        }
        v0 = n0; v1 = n1; v2 = n2; v3 = n3;
      }
    } else {
      // ---- fallback: raw row-major weights (no d_ws needed) ----
      for (int k = 0; k < DOUT_; k += 4) {
        float w[4][4];
        #pragma unroll
        for (int gi = 0; gi < 4; gi++) {
          float4 w4 = *(const float4*)&Wih[(size_t)(j + gi * 512) * DOUT_ + k];
          w[0][gi] = w4.x; w[1][gi] = w4.y; w[2][gi] = w4.z; w[3][gi] = w4.w;
        }
        #pragma unroll
        for (int r = 0; r < 8; r++) {
          float4 e4 = *(const float4*)&semb[(rbase + r) * DOUT_ + k];
          ai[r]=fmaf(e4.x,w[0][0],ai[r]); af[r]=fmaf(e4.x,w[0][1],af[r]); ag[r]=fmaf(e4.x,w[0][2],ag[r]); ao[r]=fmaf(e4.x,w[0][3],ao[r]);
          ai[r]=fmaf(e4.y,w[1][0],ai[r]); af[r]=fmaf(e4.y,w[1][1],af[r]); ag[r]=fmaf(e4.y,w[1][2],ag[r]); ao[r]=fmaf(e4.y,w[1][3],ao[r]);
          ai[r]=fmaf(e4.z,w[2][0],ai[r]); af[r]=fmaf(e4.z,w[2][1],af[r]); ag[r]=fmaf(e4.z,w[2][2],ag[r]); ao[r]=fmaf(e4.z,w[2][3],ao[r]);
          ai[r]=fmaf(e4.w,w[3][0],ai[r]); af[r]=fmaf(e4.w,w[3][1],af[r]); ag[r]=fmaf(e4.w,w[3][2],ag[r]); ao[r]=fmaf(e4.w,w[3][3],ao[r]);
        }
      }
      for (int k = 0; k < H_; k += 4) {
        float w[4][4];
        #pragma unroll
        for (int gi = 0; gi < 4; gi++) {
          float4 w4 = *(const float4*)&Whh[(size_t)(j + gi * 512) * H_ + k];
          w[0][gi] = w4.x; w[1][gi] = w4.y; w[2][gi] = w4.z; w[3][gi] = w4.w;
        }
        #pragma unroll
        for (int r = 0; r < 8; r++) {
          float4 h4 = *(const float4*)&sh[(rbase + r) * H_ + k];
          ai[r]=fmaf(h4.x,w[0][0],ai[r]); af[r]=fmaf(h4.x,w[0][1],af[r]); ag[r]=fmaf(h4.x,w[0][2],ag[r]); ao[r]=fmaf(h4.x,w[0][3],ao[r]);
          ai[r]=fmaf(h4.y,w[1][0],ai[r]); af[r]=fmaf(h4.y,w[1][1],af[r]); ag[r]=fmaf(h4.y,w[1][2],ag[r]); ao[r]=fmaf(h4.y,w[1][3],ao[r]);
          ai[r]=fmaf(h4.z,w[2][0],ai[r]); af[r]=fmaf(h4.z,w[2][1],af[r]); ag[r]=fmaf(h4.z,w[2][2],ag[r]); ao[r]=fmaf(h4.z,w[2][3],ao[r]);
          ai[r]=fmaf(h4.w,w[3][0],ai[r]); af[r]=fmaf(h4.w,w[3][1],af[r]); ag[r]=fmaf(h4.w,w[3][2],ag[r]); ao[r]=fmaf(h4.w,w[3][3],ao[r]);
        }
      }
    }

    // ---------- activations; c kept in registers ----------
    float hn[8];
    #pragma unroll
    for (int r = 0; r < 8; r++) {
      float iv = 1.f / (1.f + expf(-ai[r]));
      float fv = 1.f / (1.f + expf(-af[r]));
      float gv = tanhf(ag[r]);
      float ov = 1.f / (1.f + expf(-ao[r]));
      float cn = fv * creg[r] + iv * gv;
      creg[r]  = cn;
      hn[r]    = ov * tanhf(cn);
    }
    __syncthreads();                      // everyone done READING sh/semb
    #pragma unroll
    for (int r = 0; r < 8; r++)
      sh[(rbase + r) * H_ + j] = hn[r];
    __syncthreads();                      // new h visible

    // ---------- logits: thread owns vocab column v = t ----------
    float lacc[16];
    #pragma unroll
    for (int r = 0; r < 16; r++) lacc[r] = bov;
    if (PK) {
      float4 w = Wop[t];
      #pragma unroll 2
      for (int k4 = 0; k4 < 128; k4++) {
        const int kn = (k4 + 1 < 128) ? (k4 + 1) : 0;
        float4 n = Wop[(size_t)kn * 1024 + t];
        #pragma unroll
        for (int r = 0; r < 16; r++) {
          float4 h4 = *(const float4*)&sh[r * H_ + (k4 << 2)];
          lacc[r] = fmaf(h4.x, w.x, lacc[r]);
          lacc[r] = fmaf(h4.y, w.y, lacc[r]);
          lacc[r] = fmaf(h4.z, w.z, lacc[r]);
          lacc[r] = fmaf(h4.w, w.w, lacc[r]);
        }
        w = n;
      }
    } else {
      for (int k = 0; k < H_; k += 4) {
        float w0 = Wo[(size_t)(k + 0) * V_ + t];
        float w1 = Wo[(size_t)(k + 1) * V_ + t];
        float w2 = Wo[(size_t)(k + 2) * V_ + t];
        float w3 = Wo[(size_t)(k + 3) * V_ + t];
        #pragma unroll
        for (int r = 0; r < 16; r++) {
          float4 h4 = *(const float4*)&sh[r * H_ + k];
          lacc[r] = fmaf(h4.x, w0, lacc[r]);
          lacc[r] = fmaf(h4.y, w1, lacc[r]);
          lacc[r] = fmaf(h4.z, w2, lacc[r]);
          lacc[r] = fmaf(h4.w, w3, lacc[r]);
        }
      }
    }
    #pragma unroll
    for (int r = 0; r < 16; r++)
      out_logits[((size_t)(r0 + r) * L_ + step) * V_ + t] = lacc[r];

    // ---------- argmax (numpy semantics: first index wins on ties) ----------
    const int lane = t & 63;
    const int wv   = t >> 6;
    #pragma unroll
    for (int r = 0; r < 16; r++) {
      float bv = lacc[r];
      int   bx = t;
      #pragma unroll
      for (int off = 32; off; off >>= 1) {
        float ov = __shfl_xor(bv, off);
        int   ox = __shfl_xor(bx, off);
        if (ov > bv || (ov == bv && ox < bx)) { bv = ov; bx = ox; }
      }
      if (lane == 0) { cand_v[r * 16 + wv] = bv; cand_i[r * 16 + wv] = bx; }
    }
    __syncthreads();
    if (t < 16) {
      float bv = cand_v[t * 16 + 0];
      int   bx = cand_i[t * 16 + 0];
      #pragma unroll
      for (int c = 1; c < 16; c++) {
        float ov = cand_v[t * 16 + c];
        int   ox = cand_i[t * 16 + c];
        if (ov > bv || (ov == bv && ox < bx)) { bv = ov; bx = ox; }
      }
      sym_sh[t] = bx;
      out_seq[(size_t)(r0 + t) * L_ + step] = (float)bx;   // whole buffer is f32
    }
    __syncthreads();

    // ---------- emb feedback ----------
    {
      int r = t >> 6;
      int d = t & 63;
      semb[r * DOUT_ + d] = output_emb[(size_t)sym_sh[r] * DOUT_ + d];
    }
    __syncthreads();
  }
}

extern "C" void kernel_launch(void* const* d_in, const int* in_sizes, int n_in,
                              void* d_out, int out_size, void* d_ws, size_t ws_size,
                              hipStream_t stream) {
  const int*   x          = (const int*)  d_in[0];
  const float* input_emb  = (const float*)d_in[1];
  const float* output_emb = (const float*)d_in[2];
  const float* Wi         = (const float*)d_in[3];
  const float* bi         = (const float*)d_in[4];
  const float* W_ih       = (const float*)d_in[5];
  const float* W_hh       = (const float*)d_in[6];
  const float* b_ih       = (const float*)d_in[7];
  const float* b_hh       = (const float*)d_in[8];
  const float* Wo         = (const float*)d_in[9];
  const float* bo         = (const float*)d_in[10];
  const float* sos        = (const float*)d_in[11];
  float* out = (float*)d_out;

  const size_t n_whh = (size_t)H_ * 512;     // float4 count
  const size_t n_wih = (size_t)DOUT_ * 512;
  const size_t n_wo  = (size_t)128 * 1024;
  const size_t ws_need = (n_whh + n_wih + n_wo) * sizeof(float4);

  if (ws_size >= ws_need) {
    float4* WhhP = (float4*)d_ws;
    float4* WihP = WhhP + n_whh;
    float4* WoP  = WihP + n_wih;
    dim3 tb(32, 8);
    pack_gates<<<dim3(H_ / 32,    16), tb, 0, stream>>>(W_hh, WhhP, H_);
    pack_gates<<<dim3(DOUT_ / 32, 16), tb, 0, stream>>>(W_ih, WihP, DOUT_);
    pack_wo<<<dim3(4, 128), 256, 0, stream>>>(Wo, WoP);
    lstm_decode<true><<<B_ / ROWS, NT, 0, stream>>>(
        x, input_emb, output_emb, Wi, bi,
        (const float*)WihP, (const float*)WhhP, b_ih, b_hh,
        (const float*)WoP, bo, sos, out);
  } else {
    lstm_decode<false><<<B_ / ROWS, NT, 0, stream>>>(
        x, input_emb, output_emb, Wi, bi, W_ih, W_hh, b_ih, b_hh, Wo, bo, sos, out);
  }
}

// Round 3
// 7767.519 us; speedup vs baseline: 1.0982x; 1.0706x over previous
//
#include <hip/hip_runtime.h>
#include <math.h>

#define B_    4096
#define A_    6
#define V_    1024
#define L_    32
#define DIN_  64
#define DOUT_ 64
#define H_    512
#define G_    2048   // 4*H
#define ROWS  16
#define NT    1024

// ---------- pack W_ih / W_hh: [4*512][K] -> [K][512] float4 (i,f,g,o) ----------
__global__ void pack_gates(const float* __restrict__ W, float4* __restrict__ Wp, int K) {
  __shared__ float tile[4][32][33];
  int k0 = blockIdx.x * 32, j0 = blockIdx.y * 32;
  int tx = threadIdx.x, ty = threadIdx.y;            // 32 x 8
  #pragma unroll
  for (int gi = 0; gi < 4; gi++)
    for (int i = ty; i < 32; i += 8)
      tile[gi][i][tx] = W[(size_t)(gi * 512 + j0 + i) * K + (k0 + tx)];
  __syncthreads();
  for (int i = ty; i < 32; i += 8) {
    float4 v = make_float4(tile[0][tx][i], tile[1][tx][i], tile[2][tx][i], tile[3][tx][i]);
    Wp[(size_t)(k0 + i) * 512 + (j0 + tx)] = v;
  }
}

// ---------- pack Wo: [512][1024] -> [128][1024] float4 (k,k+1,k+2,k+3) ----------
__global__ void pack_wo(const float* __restrict__ Wo, float4* __restrict__ Wp) {
  int v  = blockIdx.x * 256 + threadIdx.x;
  int k4 = blockIdx.y;
  Wp[(size_t)k4 * 1024 + v] = make_float4(
      Wo[(size_t)(4 * k4 + 0) * 1024 + v], Wo[(size_t)(4 * k4 + 1) * 1024 + v],
      Wo[(size_t)(4 * k4 + 2) * 1024 + v], Wo[(size_t)(4 * k4 + 3) * 1024 + v]);
}

// ---------------- fused 32-step LSTM greedy decoder ----------------
// One block owns 16 batch rows for the whole sequence. No cross-block deps.
// launch_bounds(1024,4): grid==256 means exactly 1 block/CU can ever be
// resident (16 waves = 4/SIMD) -> give the allocator the full 128 VGPRs
// instead of letting it cram into 64 for an occupancy that can't exist.
template <bool PK>
__launch_bounds__(NT, 4)
__global__ void lstm_decode(
    const int*   __restrict__ x,
    const float* __restrict__ input_emb,
    const float* __restrict__ output_emb,
    const float* __restrict__ Wi,         // [A*DIN][H] raw
    const float* __restrict__ bi,
    const float* __restrict__ Wih,        // PK ? packed [64][512]f4 : raw [G][DOUT]
    const float* __restrict__ Whh,        // PK ? packed [512][512]f4 : raw [G][H]
    const float* __restrict__ b_ih,
    const float* __restrict__ b_hh,
    const float* __restrict__ Wo,         // PK ? packed [128][1024]f4 : raw [H][V]
    const float* __restrict__ bo,
    const float* __restrict__ sos,
    float* __restrict__ out)              // seq [B][L] then logits [B][L][V]
{
  __shared__ __align__(16) float sh[ROWS * H_];          // hidden state, 32 KB
  __shared__ __align__(16) float semb[ROWS * DOUT_];     // fed-back emb, 4 KB
  __shared__ __align__(16) float sbuf[ROWS * A_ * DIN_]; // prologue e / argmax cands, 24 KB

  const int t     = threadIdx.x;
  const int r0    = blockIdx.x * ROWS;
  const int j     = t & (H_ - 1);     // hidden column this thread owns (gates)
  const int rbase = (t >> 9) * 8;     // rows rbase..rbase+7
  const int vcol  = t & 511;          // vocab columns {vcol, vcol+512} (logits)
  const int wv    = t >> 6;           // wave id 0..15

  float* out_seq    = out;
  float* out_logits = out + (size_t)B_ * L_;

  // ---- prologue: gather e = input_emb[x], init emb = sos ----
  for (int idx = t; idx < ROWS * A_ * DIN_; idx += NT) {
    int r   = idx / (A_ * DIN_);
    int rem = idx - r * (A_ * DIN_);
    int a   = rem >> 6;
    int d   = rem & 63;
    int ei  = x[(r0 + r) * A_ + a];
    sbuf[idx] = input_emb[ei * DIN_ + d];
  }
  for (int idx = t; idx < ROWS * DOUT_; idx += NT)
    semb[idx] = sos[idx & 63];
  __syncthreads();

  // ---- h0 = e @ Wi + bi ----
  {
    float acc[8];
    #pragma unroll
    for (int r = 0; r < 8; r++) acc[r] = 0.f;
    for (int k = 0; k < A_ * DIN_; k++) {
      float w = Wi[(size_t)k * H_ + j];
      #pragma unroll
      for (int r = 0; r < 8; r++)
        acc[r] = fmaf(sbuf[(rbase + r) * (A_ * DIN_) + k], w, acc[r]);
    }
    float bj = bi[j];
    #pragma unroll
    for (int r = 0; r < 8; r++)
      sh[(rbase + r) * H_ + j] = acc[r] + bj;
  }
  __syncthreads();

  // persistent per-thread state
  float creg[8];
  #pragma unroll
  for (int r = 0; r < 8; r++) creg[r] = 0.f;
  const float bii = b_ih[j]        + b_hh[j];
  const float bff = b_ih[j + 512]  + b_hh[j + 512];
  const float bgg = b_ih[j + 1024] + b_hh[j + 1024];
  const float boo = b_ih[j + 1536] + b_hh[j + 1536];
  const float bovA = bo[vcol];
  const float bovB = bo[vcol + 512];

  float* cand_v = sbuf;                  // [16 rows][8 waves]
  int*   cand_i = (int*)(sbuf + 128);

  const float4* WpE = (const float4*)Wih;   // [64][512]  (PK)
  const float4* WpH = (const float4*)Whh;   // [512][512] (PK)
  const float4* Wop = (const float4*)Wo;    // [128][1024](PK)

  for (int step = 0; step < L_; step++) {
    // ---------- gates = bias + emb @ W_ih^T + h @ W_hh^T ----------
    float ai[8], af[8], ag[8], ao[8];
    #pragma unroll
    for (int r = 0; r < 8; r++) { ai[r] = bii; af[r] = bff; ag[r] = bgg; ao[r] = boo; }

    if (PK) {
      // ---- emb part (K = 64), packed float4 weights ----
      for (int k = 0; k < DOUT_; k += 4) {
        float4 w0 = WpE[(size_t)(k + 0) * 512 + j];
        float4 w1 = WpE[(size_t)(k + 1) * 512 + j];
        float4 w2 = WpE[(size_t)(k + 2) * 512 + j];
        float4 w3 = WpE[(size_t)(k + 3) * 512 + j];
        #pragma unroll
        for (int r = 0; r < 8; r++) {
          float4 e4 = *(const float4*)&semb[(rbase + r) * DOUT_ + k];
          ai[r]=fmaf(e4.x,w0.x,ai[r]); af[r]=fmaf(e4.x,w0.y,af[r]); ag[r]=fmaf(e4.x,w0.z,ag[r]); ao[r]=fmaf(e4.x,w0.w,ao[r]);
          ai[r]=fmaf(e4.y,w1.x,ai[r]); af[r]=fmaf(e4.y,w1.y,af[r]); ag[r]=fmaf(e4.y,w1.z,ag[r]); ao[r]=fmaf(e4.y,w1.w,ao[r]);
          ai[r]=fmaf(e4.z,w2.x,ai[r]); af[r]=fmaf(e4.z,w2.y,af[r]); ag[r]=fmaf(e4.z,w2.z,ag[r]); ao[r]=fmaf(e4.z,w2.w,ao[r]);
          ai[r]=fmaf(e4.w,w3.x,ai[r]); af[r]=fmaf(e4.w,w3.y,af[r]); ag[r]=fmaf(e4.w,w3.z,ag[r]); ao[r]=fmaf(e4.w,w3.w,ao[r]);
        }
      }
      // ---- h part (K = 512), depth-1 prefetch (now has VGPR room) ----
      float4 v0 = WpH[0 * 512 + j], v1 = WpH[1 * 512 + j],
             v2 = WpH[2 * 512 + j], v3 = WpH[3 * 512 + j];
      #pragma unroll 2
      for (int k = 0; k < H_; k += 4) {
        const int kn = (k + 4 < H_) ? (k + 4) : 0;
        float4 n0 = WpH[(size_t)(kn + 0) * 512 + j];
        float4 n1 = WpH[(size_t)(kn + 1) * 512 + j];
        float4 n2 = WpH[(size_t)(kn + 2) * 512 + j];
        float4 n3 = WpH[(size_t)(kn + 3) * 512 + j];
        #pragma unroll
        for (int r = 0; r < 8; r++) {
          float4 h4 = *(const float4*)&sh[(rbase + r) * H_ + k];
          ai[r]=fmaf(h4.x,v0.x,ai[r]); af[r]=fmaf(h4.x,v0.y,af[r]); ag[r]=fmaf(h4.x,v0.z,ag[r]); ao[r]=fmaf(h4.x,v0.w,ao[r]);
          ai[r]=fmaf(h4.y,v1.x,ai[r]); af[r]=fmaf(h4.y,v1.y,af[r]); ag[r]=fmaf(h4.y,v1.z,ag[r]); ao[r]=fmaf(h4.y,v1.w,ao[r]);
          ai[r]=fmaf(h4.z,v2.x,ai[r]); af[r]=fmaf(h4.z,v2.y,af[r]); ag[r]=fmaf(h4.z,v2.z,ag[r]); ao[r]=fmaf(h4.z,v2.w,ao[r]);
          ai[r]=fmaf(h4.w,v3.x,ai[r]); af[r]=fmaf(h4.w,v3.y,af[r]); ag[r]=fmaf(h4.w,v3.z,ag[r]); ao[r]=fmaf(h4.w,v3.w,ao[r]);
        }
        v0 = n0; v1 = n1; v2 = n2; v3 = n3;
      }
    } else {
      // ---- fallback: raw row-major weights ----
      for (int k = 0; k < DOUT_; k += 4) {
        float w[4][4];
        #pragma unroll
        for (int gi = 0; gi < 4; gi++) {
          float4 w4 = *(const float4*)&Wih[(size_t)(j + gi * 512) * DOUT_ + k];
          w[0][gi] = w4.x; w[1][gi] = w4.y; w[2][gi] = w4.z; w[3][gi] = w4.w;
        }
        #pragma unroll
        for (int r = 0; r < 8; r++) {
          float4 e4 = *(const float4*)&semb[(rbase + r) * DOUT_ + k];
          ai[r]=fmaf(e4.x,w[0][0],ai[r]); af[r]=fmaf(e4.x,w[0][1],af[r]); ag[r]=fmaf(e4.x,w[0][2],ag[r]); ao[r]=fmaf(e4.x,w[0][3],ao[r]);
          ai[r]=fmaf(e4.y,w[1][0],ai[r]); af[r]=fmaf(e4.y,w[1][1],af[r]); ag[r]=fmaf(e4.y,w[1][2],ag[r]); ao[r]=fmaf(e4.y,w[1][3],ao[r]);
          ai[r]=fmaf(e4.z,w[2][0],ai[r]); af[r]=fmaf(e4.z,w[2][1],af[r]); ag[r]=fmaf(e4.z,w[2][2],ag[r]); ao[r]=fmaf(e4.z,w[2][3],ao[r]);
          ai[r]=fmaf(e4.w,w[3][0],ai[r]); af[r]=fmaf(e4.w,w[3][1],af[r]); ag[r]=fmaf(e4.w,w[3][2],ag[r]); ao[r]=fmaf(e4.w,w[3][3],ao[r]);
        }
      }
      for (int k = 0; k < H_; k += 4) {
        float w[4][4];
        #pragma unroll
        for (int gi = 0; gi < 4; gi++) {
          float4 w4 = *(const float4*)&Whh[(size_t)(j + gi * 512) * H_ + k];
          w[0][gi] = w4.x; w[1][gi] = w4.y; w[2][gi] = w4.z; w[3][gi] = w4.w;
        }
        #pragma unroll
        for (int r = 0; r < 8; r++) {
          float4 h4 = *(const float4*)&sh[(rbase + r) * H_ + k];
          ai[r]=fmaf(h4.x,w[0][0],ai[r]); af[r]=fmaf(h4.x,w[0][1],af[r]); ag[r]=fmaf(h4.x,w[0][2],ag[r]); ao[r]=fmaf(h4.x,w[0][3],ao[r]);
          ai[r]=fmaf(h4.y,w[1][0],ai[r]); af[r]=fmaf(h4.y,w[1][1],af[r]); ag[r]=fmaf(h4.y,w[1][2],ag[r]); ao[r]=fmaf(h4.y,w[1][3],ao[r]);
          ai[r]=fmaf(h4.z,w[2][0],ai[r]); af[r]=fmaf(h4.z,w[2][1],af[r]); ag[r]=fmaf(h4.z,w[2][2],ag[r]); ao[r]=fmaf(h4.z,w[2][3],ao[r]);
          ai[r]=fmaf(h4.w,w[3][0],ai[r]); af[r]=fmaf(h4.w,w[3][1],af[r]); ag[r]=fmaf(h4.w,w[3][2],ao[r]*0.f+ag[r]); ao[r]=fmaf(h4.w,w[3][3],ao[r]);
        }
      }
    }

    // ---------- activations; c kept in registers ----------
    float hn[8];
    #pragma unroll
    for (int r = 0; r < 8; r++) {
      float iv = 1.f / (1.f + expf(-ai[r]));
      float fv = 1.f / (1.f + expf(-af[r]));
      float gv = tanhf(ag[r]);
      float ov = 1.f / (1.f + expf(-ao[r]));
      float cn = fv * creg[r] + iv * gv;
      creg[r]  = cn;
      hn[r]    = ov * tanhf(cn);
    }
    __syncthreads();                      // everyone done READING sh/semb
    #pragma unroll
    for (int r = 0; r < 8; r++)
      sh[(rbase + r) * H_ + j] = hn[r];
    __syncthreads();                      // new h visible

    // ---------- logits: thread owns vocab cols {vcol, vcol+512} x 8 rows ----------
    float lacc[16];
    #pragma unroll
    for (int r = 0; r < 8; r++) { lacc[r * 2] = bovA; lacc[r * 2 + 1] = bovB; }
    if (PK) {
      float4 wA = Wop[vcol], wB = Wop[vcol + 512];
      #pragma unroll 2
      for (int k4 = 0; k4 < 128; k4++) {
        const int kn = (k4 + 1 < 128) ? (k4 + 1) : 0;
        float4 nA = Wop[(size_t)kn * 1024 + vcol];
        float4 nB = Wop[(size_t)kn * 1024 + vcol + 512];
        #pragma unroll
        for (int r = 0; r < 8; r++) {
          float4 h4 = *(const float4*)&sh[(rbase + r) * H_ + (k4 << 2)];
          lacc[r*2]   = fmaf(h4.x, wA.x, lacc[r*2]);
          lacc[r*2]   = fmaf(h4.y, wA.y, lacc[r*2]);
          lacc[r*2]   = fmaf(h4.z, wA.z, lacc[r*2]);
          lacc[r*2]   = fmaf(h4.w, wA.w, lacc[r*2]);
          lacc[r*2+1] = fmaf(h4.x, wB.x, lacc[r*2+1]);
          lacc[r*2+1] = fmaf(h4.y, wB.y, lacc[r*2+1]);
          lacc[r*2+1] = fmaf(h4.z, wB.z, lacc[r*2+1]);
          lacc[r*2+1] = fmaf(h4.w, wB.w, lacc[r*2+1]);
        }
        wA = nA; wB = nB;
      }
    } else {
      for (int k = 0; k < H_; k += 4) {
        float wa0 = Wo[(size_t)(k+0)*V_ + vcol], wb0 = Wo[(size_t)(k+0)*V_ + vcol + 512];
        float wa1 = Wo[(size_t)(k+1)*V_ + vcol], wb1 = Wo[(size_t)(k+1)*V_ + vcol + 512];
        float wa2 = Wo[(size_t)(k+2)*V_ + vcol], wb2 = Wo[(size_t)(k+2)*V_ + vcol + 512];
        float wa3 = Wo[(size_t)(k+3)*V_ + vcol], wb3 = Wo[(size_t)(k+3)*V_ + vcol + 512];
        #pragma unroll
        for (int r = 0; r < 8; r++) {
          float4 h4 = *(const float4*)&sh[(rbase + r) * H_ + k];
          lacc[r*2]   = fmaf(h4.x, wa0, lacc[r*2]);
          lacc[r*2]   = fmaf(h4.y, wa1, lacc[r*2]);
          lacc[r*2]   = fmaf(h4.z, wa2, lacc[r*2]);
          lacc[r*2]   = fmaf(h4.w, wa3, lacc[r*2]);
          lacc[r*2+1] = fmaf(h4.x, wb0, lacc[r*2+1]);
          lacc[r*2+1] = fmaf(h4.y, wb1, lacc[r*2+1]);
          lacc[r*2+1] = fmaf(h4.z, wb2, lacc[r*2+1]);
          lacc[r*2+1] = fmaf(h4.w, wb3, lacc[r*2+1]);
        }
      }
    }
    // nontemporal stores: logits are never re-read; skip RFO + L2 pollution
    #pragma unroll
    for (int r = 0; r < 8; r++) {
      float* p = &out_logits[((size_t)(r0 + rbase + r) * L_ + step) * V_ + vcol];
      __builtin_nontemporal_store(lacc[r*2],     p);
      __builtin_nontemporal_store(lacc[r*2 + 1], p + 512);
    }

    // ---------- argmax (numpy semantics: first index wins on ties) ----------
    #pragma unroll
    for (int r = 0; r < 8; r++) {
      float bv = lacc[r*2];
      int   bx = vcol;
      float v2 = lacc[r*2 + 1];
      if (v2 > bv) { bv = v2; bx = vcol + 512; }   // tie keeps smaller idx
      #pragma unroll
      for (int off = 32; off; off >>= 1) {
        float ov = __shfl_xor(bv, off);
        int   ox = __shfl_xor(bx, off);
        if (ov > bv || (ov == bv && ox < bx)) { bv = ov; bx = ox; }
      }
      if ((t & 63) == 0) {
        cand_v[(rbase + r) * 8 + (wv & 7)] = bv;
        cand_i[(rbase + r) * 8 + (wv & 7)] = bx;
      }
    }
    __syncthreads();

    // ---------- winner scan (redundant per emb-thread; kills a barrier) ----------
    {
      int r = t >> 6;        // 0..15
      int d = t & 63;
      float bv = cand_v[r * 8];
      int   bx = cand_i[r * 8];
      #pragma unroll
      for (int c = 1; c < 8; c++) {
        float ov = cand_v[r * 8 + c];
        int   ox = cand_i[r * 8 + c];
        if (ov > bv || (ov == bv && ox < bx)) { bv = ov; bx = ox; }
      }
      if (d == 0)
        out_seq[(size_t)(r0 + r) * L_ + step] = (float)bx;
      semb[r * DOUT_ + d] = output_emb[(size_t)bx * DOUT_ + d];
    }
    __syncthreads();
  }
}

extern "C" void kernel_launch(void* const* d_in, const int* in_sizes, int n_in,
                              void* d_out, int out_size, void* d_ws, size_t ws_size,
                              hipStream_t stream) {
  const int*   x          = (const int*)  d_in[0];
  const float* input_emb  = (const float*)d_in[1];
  const float* output_emb = (const float*)d_in[2];
  const float* Wi         = (const float*)d_in[3];
  const float* bi         = (const float*)d_in[4];
  const float* W_ih       = (const float*)d_in[5];
  const float* W_hh       = (const float*)d_in[6];
  const float* b_ih       = (const float*)d_in[7];
  const float* b_hh       = (const float*)d_in[8];
  const float* Wo         = (const float*)d_in[9];
  const float* bo         = (const float*)d_in[10];
  const float* sos        = (const float*)d_in[11];
  float* out = (float*)d_out;

  const size_t n_whh = (size_t)H_ * 512;     // float4 count
  const size_t n_wih = (size_t)DOUT_ * 512;
  const size_t n_wo  = (size_t)128 * 1024;
  const size_t ws_need = (n_whh + n_wih + n_wo) * sizeof(float4);

  if (ws_size >= ws_need) {
    float4* WhhP = (float4*)d_ws;
    float4* WihP = WhhP + n_whh;
    float4* WoP  = WihP + n_wih;
    dim3 tb(32, 8);
    pack_gates<<<dim3(H_ / 32,    16), tb, 0, stream>>>(W_hh, WhhP, H_);
    pack_gates<<<dim3(DOUT_ / 32, 16), tb, 0, stream>>>(W_ih, WihP, DOUT_);
    pack_wo<<<dim3(4, 128), 256, 0, stream>>>(Wo, WoP);
    lstm_decode<true><<<B_ / ROWS, NT, 0, stream>>>(
        x, input_emb, output_emb, Wi, bi,
        (const float*)WihP, (const float*)WhhP, b_ih, b_hh,
        (const float*)WoP, bo, sos, out);
  } else {
    lstm_decode<false><<<B_ / ROWS, NT, 0, stream>>>(
        x, input_emb, output_emb, Wi, bi, W_ih, W_hh, b_ih, b_hh, Wo, bo, sos, out);
  }
}